// Round 6
// baseline (155.315 us; speedup 1.0000x reference)
//
#include <hip/hip_runtime.h>
#include <math.h>

typedef unsigned short u16;
typedef unsigned int   u32;
typedef __bf16 bf16x8 __attribute__((ext_vector_type(8)));
typedef float  f32x4  __attribute__((ext_vector_type(4)));

#define B_ROWS 16384
#define PC 16
#define EPS_SIM 1e-4f
#define LOG_MIN_F (-18.420680743952367f)
#define KL_IDX  (B_ROWS + B_ROWS * 512)   // 8404992
#define OR_IDX  (KL_IDX + 1)

// direct global->LDS async copy, 16B per lane (lds dest = uniform base + lane*16)
#define GLD16(gp, lp) __builtin_amdgcn_global_load_lds( \
    (const __attribute__((address_space(1))) void*)(gp), \
    (__attribute__((address_space(3))) void*)(lp), 16, 0, 0)

__device__ inline u16 f2bf(float f) {
    u32 u = __float_as_uint(f);
    return (u16)((u + 0x7FFFu + ((u >> 16) & 1u)) >> 16);
}
__device__ inline float bf2f(u16 h) { return __uint_as_float(((u32)h) << 16); }

// ---------------------------------------------------------------------------
__global__ void init_kernel(float* __restrict__ S, float* __restrict__ Mn,
                            float* __restrict__ out)
{
    int i = blockIdx.x * 256 + threadIdx.x;
    if (i < B_ROWS) { S[i] = 0.0f; Mn[i] = 0.0f; }
    if (i == 0) { out[KL_IDX] = 0.0f; out[OR_IDX] = 0.0f; }
}

// fp32 -> (bf16 hi, bf16 lo) arrays, 4 elems/thread
__global__ __launch_bounds__(256)
void split_kernel(const float* __restrict__ src, u16* __restrict__ hi,
                  u16* __restrict__ lo, int n4)
{
    int i = blockIdx.x * 256 + threadIdx.x;
    if (i >= n4) return;
    float4 v = ((const float4*)src)[i];
    float f[4] = {v.x, v.y, v.z, v.w};
    u16 h[4], l[4];
#pragma unroll
    for (int k = 0; k < 4; ++k) {
        h[k] = f2bf(f[k]);
        l[k] = f2bf(f[k] - bf2f(h[k]));
    }
    ((ushort4*)hi)[i] = make_ushort4(h[0], h[1], h[2], h[3]);
    ((ushort4*)lo)[i] = make_ushort4(l[0], l[1], l[2], l[3]);
}

// pnorm[p] = |protos[p]|^2 ; 2 blocks x 256 threads, 4 lanes per proto row
__global__ __launch_bounds__(256)
void pnorm_kernel(const float* __restrict__ protos, float* __restrict__ pnorm)
{
    int t = blockIdx.x * 256 + threadIdx.x;
    int row = t >> 2, q = t & 3;
    const float* pr = protos + (size_t)row * 256 + q * 64;
    float s = 0.f;
#pragma unroll
    for (int j = 0; j < 16; ++j) {
        float4 v = *(const float4*)(pr + j * 4);
        s = fmaf(v.x, v.x, s); s = fmaf(v.y, v.y, s);
        s = fmaf(v.z, v.z, s); s = fmaf(v.w, v.w, s);
    }
    s += __shfl_xor(s, 1, 64);
    s += __shfl_xor(s, 2, 64);
    if (q == 0) pnorm[row] = s;
}

// ---------------------------------------------------------------------------
// Split-bf16 MFMA GEMM, BM=64 x BN=128 tile, BK=32, 4 waves (2x2), 24KB LDS.
// Two-barrier loop: barrier -> ds_read frags -> barrier -> stage(tk+1) -> MFMA.
// MODE 0: relu -> split store
// MODE 3: tanh -> f32 store
// MODE 4: y<2 mu split store + |mu|^2 row-reduce; y>=2 logVar -> S row-reduce
// MODE 5: y<2 relu split store (dh); y==2 proto-distance epilogue
// ---------------------------------------------------------------------------
template<int MODE>
__global__ __launch_bounds__(256, 4)
void gemm_mfma(const u16* __restrict__ Ah_g, const u16* __restrict__ Al_g,
               const u16* __restrict__ Bh_g, const u16* __restrict__ Bl_g,
               const u16* __restrict__ Ph,   const u16* __restrict__ Pl,
               const float* __restrict__ bias,
               u16* __restrict__ Ch, u16* __restrict__ Cl,
               float* __restrict__ Cf,
               float* __restrict__ Srow, float* __restrict__ Mnorm,
               const int* __restrict__ tcls, const float* __restrict__ pnorm,
               const float* __restrict__ Wlast,
               float* __restrict__ out, float* __restrict__ klrow,
               int K, int ldc)
{
    __shared__ __align__(16) u16 LAh[64][32];
    __shared__ __align__(16) u16 LAl[64][32];
    __shared__ __align__(16) u16 LBh[128][32];
    __shared__ __align__(16) u16 LBl[128][32];

    const int t = threadIdx.x, lane = t & 63, wave = t >> 6;
    const int wm = wave >> 1, wn = wave & 1;
    const int bm = blockIdx.x * 64;
    const int y  = blockIdx.y;
    const bool proto = (MODE == 5) && (y == 2);
    const int bn = proto ? 0 : y * 128;
    const u16* Bh = proto ? Ph : Bh_g;
    const u16* Bl = proto ? Pl : Bl_g;
    const int rA = lane & 15, g = lane >> 4;
    const int srow = lane >> 2, cp = lane & 3;

    f32x4 acc[2][4];
    const f32x4 z4 = {0.f, 0.f, 0.f, 0.f};
#pragma unroll
    for (int i = 0; i < 2; ++i)
#pragma unroll
        for (int j = 0; j < 4; ++j) acc[i][j] = z4;

    auto stage = [&](int kt) {
        {   // A: one 16-row slab per wave (rows wave*16 .. +15)
            int row = wave * 16 + srow;
            int lc  = (cp - (row >> 1)) & 3;              // inverse swizzle on SOURCE
            size_t goff = (size_t)(bm + row) * K + kt * 32 + lc * 8;
            GLD16(Ah_g + goff, &LAh[wave * 16][0]);
            GLD16(Al_g + goff, &LAl[wave * 16][0]);
        }
#pragma unroll
        for (int jj = 0; jj < 2; ++jj) {   // B: two 16-row slabs per wave
            int row = wave * 32 + jj * 16 + srow;
            int lc  = (cp - (row >> 1)) & 3;
            size_t goff = (size_t)(bn + row) * K + kt * 32 + lc * 8;
            GLD16(Bh + goff, &LBh[wave * 32 + jj * 16][0]);
            GLD16(Bl + goff, &LBl[wave * 32 + jj * 16][0]);
        }
    };

    const int T = K / 32;
    stage(0);
    for (int tk = 0; tk < T; ++tk) {
        __syncthreads();                 // vmcnt(0) drained: tile tk in LDS

        bf16x8 aH[2], aL[2], bH[4], bL[4];
#pragma unroll
        for (int i = 0; i < 2; ++i) {
            int m  = wm * 32 + i * 16 + rA;
            int cm = ((g + (m >> 1)) & 3) * 8;            // swizzled READ
            aH[i] = *(const bf16x8*)&LAh[m][cm];
            aL[i] = *(const bf16x8*)&LAl[m][cm];
        }
#pragma unroll
        for (int j = 0; j < 4; ++j) {
            int n  = wn * 64 + j * 16 + rA;
            int cn = ((g + (n >> 1)) & 3) * 8;
            bH[j] = *(const bf16x8*)&LBh[n][cn];
            bL[j] = *(const bf16x8*)&LBl[n][cn];
        }

        __syncthreads();                 // all reads done; safe to overwrite
        if (tk + 1 < T) stage(tk + 1);   // loads fly during the MFMAs below

#pragma unroll
        for (int i = 0; i < 2; ++i)
#pragma unroll
            for (int j = 0; j < 4; ++j) {
                acc[i][j] = __builtin_amdgcn_mfma_f32_16x16x32_bf16(aH[i], bH[j], acc[i][j], 0, 0, 0);
                acc[i][j] = __builtin_amdgcn_mfma_f32_16x16x32_bf16(aL[i], bH[j], acc[i][j], 0, 0, 0);
                acc[i][j] = __builtin_amdgcn_mfma_f32_16x16x32_bf16(aH[i], bL[j], acc[i][j], 0, 0, 0);
            }
    }

    if (proto) {
        // d^2 = |mu|^2 + |p|^2 - 2*cross for the class slab cols cls*16..+15
        float pn[4], wl[4];
#pragma unroll
        for (int j = 0; j < 4; ++j) {
            int col = wn * 64 + j * 16 + rA;
            pn[j] = pnorm[col];
            wl[j] = Wlast[col];
        }
#pragma unroll
        for (int i = 0; i < 2; ++i)
#pragma unroll
            for (int r = 0; r < 4; ++r) {
                int row = bm + wm * 32 + i * 16 + g * 4 + r;
                int cls = tcls[row];
                int jsel = cls & 3;
                bool owner = ((cls >> 2) == wn);
                float cv = 0.f, pnv = 0.f, wlv = 0.f;
#pragma unroll
                for (int j = 0; j < 4; ++j) {
                    bool sel = (j == jsel);
                    cv  = sel ? acc[i][j][r] : cv;
                    pnv = sel ? pn[j] : pnv;
                    wlv = sel ? wl[j] : wlv;
                }
                float dd  = fmaxf(Mnorm[row] + pnv - 2.f * cv, 0.f);
                float d   = sqrtf(dd);
                float sim = __logf((d + 1.0f) / (d + EPS_SIM));
                float kl  = Srow[row] + dd * (0.5f / 256.f);
                float klw = kl * sim;
                float num = klw;
                float den = (klw > 0.0f) ? sim : 0.0f;
                float ov  = sim * wlv;
                num += __shfl_xor(num, 1, 64); den += __shfl_xor(den, 1, 64); ov += __shfl_xor(ov, 1, 64);
                num += __shfl_xor(num, 2, 64); den += __shfl_xor(den, 2, 64); ov += __shfl_xor(ov, 2, 64);
                num += __shfl_xor(num, 4, 64); den += __shfl_xor(den, 4, 64); ov += __shfl_xor(ov, 4, 64);
                num += __shfl_xor(num, 8, 64); den += __shfl_xor(den, 8, 64); ov += __shfl_xor(ov, 8, 64);
                if (owner && rA == 0) {
                    out[row]   = ov;
                    klrow[row] = num / den;
                }
            }
        return;
    }

    float bv[4];
#pragma unroll
    for (int j = 0; j < 4; ++j) bv[j] = bias[bn + wn * 64 + j * 16 + rA];

    if (MODE == 4 && y >= 2) {
        // logVar columns: S[row] += mean_l(0.5 e^lv - 0.5 lv - 0.5)
#pragma unroll
        for (int i = 0; i < 2; ++i)
#pragma unroll
            for (int r = 0; r < 4; ++r) {
                int row = bm + wm * 32 + i * 16 + g * 4 + r;
                float s = 0.f;
#pragma unroll
                for (int j = 0; j < 4; ++j) {
                    float lv = acc[i][j][r] + bv[j];
                    lv = fminf(fmaxf(lv, LOG_MIN_F), -LOG_MIN_F);
                    s += 0.5f * __expf(lv) - 0.5f * lv - 0.5f;
                }
                s += __shfl_xor(s, 1, 64); s += __shfl_xor(s, 2, 64);
                s += __shfl_xor(s, 4, 64); s += __shfl_xor(s, 8, 64);
                if (rA == 0) atomicAdd(&Srow[row], s * (1.f / 256.f));
            }
        return;
    }

#pragma unroll
    for (int i = 0; i < 2; ++i)
#pragma unroll
        for (int r = 0; r < 4; ++r) {
            size_t row = bm + wm * 32 + i * 16 + g * 4 + r;
            float sq = 0.f;
#pragma unroll
            for (int j = 0; j < 4; ++j) {
                int col = bn + wn * 64 + j * 16 + rA;
                float v = acc[i][j][r] + bv[j];
                if (MODE == 0 || MODE == 5) v = fmaxf(v, 0.f);
                if (MODE == 3) {
                    float e = __expf(2.f * v);
                    Cf[row * ldc + col] = 1.f - 2.f / (e + 1.f);
                } else {
                    u16 hh = f2bf(v);
                    u16 ll = f2bf(v - bf2f(hh));
                    Ch[row * ldc + col] = hh;
                    Cl[row * ldc + col] = ll;
                    if (MODE == 4) sq = fmaf(v, v, sq);
                }
            }
            if (MODE == 4) {   // |mu|^2 partial for this wave's 64 cols
                sq += __shfl_xor(sq, 1, 64); sq += __shfl_xor(sq, 2, 64);
                sq += __shfl_xor(sq, 4, 64); sq += __shfl_xor(sq, 8, 64);
                if (rA == 0) atomicAdd(&Mnorm[row], sq);
            }
        }
}

__global__ __launch_bounds__(256)
void reduce_kl(const float* __restrict__ klrow, float* __restrict__ kl_out)
{
    int i = blockIdx.x * 256 + threadIdx.x;
    float v = klrow[i];
#pragma unroll
    for (int off = 32; off; off >>= 1) v += __shfl_xor(v, off, 64);
    __shared__ float red[4];
    int lane = threadIdx.x & 63, w = threadIdx.x >> 6;
    if (lane == 0) red[w] = v;
    __syncthreads();
    if (threadIdx.x == 0)
        atomicAdd(kl_out, (red[0] + red[1] + red[2] + red[3]) * (1.0f / (float)B_ROWS));
}

__global__ __launch_bounds__(256)
void ortho_kernel(const float* __restrict__ protos, float* __restrict__ ortho_out)
{
    int c = blockIdx.x;
    __shared__ float pk[PC][257];
    __shared__ float red[256];
    int t = threadIdx.x;
    for (int i = t; i < PC * 256; i += 256)
        pk[i >> 8][i & 255] = protos[c * PC * 256 + i];
    __syncthreads();
    float mean = 0.0f;
    for (int i = 0; i < PC; ++i) mean += pk[i][t];
    mean *= (1.0f / (float)PC);
    for (int i = 0; i < PC; ++i) pk[i][t] -= mean;
    __syncthreads();
    int i = t >> 4, j = t & 15;
    float gg = 0.0f;
    for (int l = 0; l < 256; ++l) gg += pk[i][l] * pk[j][l];
    gg -= (i == j) ? 1.0f : 0.0f;
    red[t] = gg * gg;
    __syncthreads();
    for (int s = 128; s; s >>= 1) { if (t < s) red[t] += red[t + s]; __syncthreads(); }
    if (t == 0) atomicAdd(ortho_out, sqrtf(red[0]) * (1.0f / 8.0f));
}

// ---------------------------------------------------------------------------
extern "C" void kernel_launch(void* const* d_in, const int* in_sizes, int n_in,
                              void* d_out, int out_size, void* d_ws, size_t ws_size,
                              hipStream_t stream)
{
    const float* x      = (const float*)d_in[0];
    const int*   tcls   = (const int*)  d_in[1];
    const float* protos = (const float*)d_in[2];
    const float* W1     = (const float*)d_in[3];
    const float* b1     = (const float*)d_in[4];
    const float* W2     = (const float*)d_in[5];
    const float* b2     = (const float*)d_in[6];
    const float* Wd1    = (const float*)d_in[7];
    const float* bd1    = (const float*)d_in[8];
    const float* Wd2    = (const float*)d_in[9];
    const float* bd2    = (const float*)d_in[10];
    const float* Wlast  = (const float*)d_in[11];

    float* out     = (float*)d_out;
    float* decoded = out + B_ROWS;

    // h (split bf16) lives in d_out's decoded region (33.55MB), overwritten by G4
    u16* h_h = (u16*)decoded;
    u16* h_l = h_h + 8388608;

    // workspace overlays: x region (32MB) reused for mu + dh after G1
    u16* wsu  = (u16*)d_ws;
    u16* x_h  = wsu;
    u16* x_l  = wsu + 8388608;
    u16* mu_h = wsu;
    u16* mu_l = wsu + 4194304;
    u16* dh_h = wsu + 8388608;
    u16* dh_l = wsu + 12582912;

    float* S     = (float*)((char*)d_ws + 33554432);
    float* klrow = S + 16384;
    u16* w = (u16*)(klrow + 16384);
    u16 *W1h = w, *W1l = w + 262144, *W2h = w + 524288, *W2l = w + 786432;
    u16 *Wd1h = w + 1048576, *Wd1l = w + 1114112, *Wd2h = w + 1179648, *Wd2l = w + 1310720;
    u16 *ph = w + 1441792, *pl = ph + 32768;       // protos split (128x256)
    float* munorm = (float*)(pl + 32768);          // 16384 f32
    float* pnorm  = munorm + 16384;                // 128 f32

    hipLaunchKernelGGL(init_kernel, dim3(64), dim3(256), 0, stream, S, munorm, out);

    hipLaunchKernelGGL(split_kernel, dim3(8192), dim3(256), 0, stream, x,   x_h,  x_l,  2097152);
    hipLaunchKernelGGL(split_kernel, dim3(256),  dim3(256), 0, stream, W1,  W1h,  W1l,  65536);
    hipLaunchKernelGGL(split_kernel, dim3(256),  dim3(256), 0, stream, W2,  W2h,  W2l,  65536);
    hipLaunchKernelGGL(split_kernel, dim3(64),   dim3(256), 0, stream, Wd1, Wd1h, Wd1l, 16384);
    hipLaunchKernelGGL(split_kernel, dim3(128),  dim3(256), 0, stream, Wd2, Wd2h, Wd2l, 32768);
    hipLaunchKernelGGL(split_kernel, dim3(32),   dim3(256), 0, stream, protos, ph, pl, 8192);
    hipLaunchKernelGGL(pnorm_kernel, dim3(2),    dim3(256), 0, stream, protos, pnorm);

    // G1: h = relu(x @ W1^T + b1) -> split bf16
    hipLaunchKernelGGL((gemm_mfma<0>), dim3(256, 4), dim3(256), 0, stream,
                       x_h, x_l, W1h, W1l, (u16*)nullptr, (u16*)nullptr, b1,
                       h_h, h_l, (float*)nullptr, (float*)nullptr, (float*)nullptr,
                       (int*)nullptr, (float*)nullptr, (float*)nullptr,
                       (float*)nullptr, (float*)nullptr, 512, 512);
    // G2: conv = h @ W2^T + b2 -> mu split + munorm (y<2); S row-sums (y>=2)
    hipLaunchKernelGGL((gemm_mfma<4>), dim3(256, 4), dim3(256), 0, stream,
                       h_h, h_l, W2h, W2l, (u16*)nullptr, (u16*)nullptr, b2,
                       mu_h, mu_l, (float*)nullptr, S, munorm,
                       (int*)nullptr, (float*)nullptr, (float*)nullptr,
                       (float*)nullptr, (float*)nullptr, 512, 256);
    // G3': y<2: dh = relu(mu @ Wd1^T + bd1); y==2: proto distances + sim/kl/out
    hipLaunchKernelGGL((gemm_mfma<5>), dim3(256, 3), dim3(256), 0, stream,
                       mu_h, mu_l, Wd1h, Wd1l, ph, pl, bd1,
                       dh_h, dh_l, (float*)nullptr, S, munorm,
                       tcls, pnorm, Wlast, out, klrow, 256, 256);
    hipLaunchKernelGGL(reduce_kl, dim3(64), dim3(256), 0, stream, klrow, out + KL_IDX);
    // G4: decoded = tanh(dh @ Wd2^T + bd2) -> f32 (overwrites h region)
    hipLaunchKernelGGL((gemm_mfma<3>), dim3(256, 4), dim3(256), 0, stream,
                       dh_h, dh_l, Wd2h, Wd2l, (u16*)nullptr, (u16*)nullptr, bd2,
                       (u16*)nullptr, (u16*)nullptr, decoded, (float*)nullptr, (float*)nullptr,
                       (int*)nullptr, (float*)nullptr, (float*)nullptr,
                       (float*)nullptr, (float*)nullptr, 256, 512);
    hipLaunchKernelGGL(ortho_kernel, dim3(8), dim3(256), 0, stream, protos, out + OR_IDX);
}

// Round 7
// 140.162 us; speedup vs baseline: 1.1081x; 1.1081x over previous
//
#include <hip/hip_runtime.h>
#include <math.h>

typedef unsigned short u16;
typedef unsigned int   u32;
typedef __bf16 bf16x8 __attribute__((ext_vector_type(8)));
typedef float  f32x4  __attribute__((ext_vector_type(4)));

#define B_ROWS 16384
#define PC 16
#define EPS_SIM 1e-4f
#define LOG_MIN_F (-18.420680743952367f)
#define KL_IDX  (B_ROWS + B_ROWS * 512)   // 8404992
#define OR_IDX  (KL_IDX + 1)

// direct global->LDS async copy, 16B per lane (lds dest = uniform base + lane*16)
#define GLD16(gp, lp) __builtin_amdgcn_global_load_lds( \
    (const __attribute__((address_space(1))) void*)(gp), \
    (__attribute__((address_space(3))) void*)(lp), 16, 0, 0)

__device__ inline u16 f2bf(float f) {
    u32 u = __float_as_uint(f);
    return (u16)((u + 0x7FFFu + ((u >> 16) & 1u)) >> 16);
}
__device__ inline float bf2f(u16 h) { return __uint_as_float(((u32)h) << 16); }

// ---------------------------------------------------------------------------
// prep: ALL input splits + pnorm + init in ONE launch (block-range dispatch)
// ---------------------------------------------------------------------------
__device__ __forceinline__ void split4(const float* __restrict__ src,
                                       u16* __restrict__ hi, u16* __restrict__ lo,
                                       int i)
{
    float4 v = ((const float4*)src)[i];
    float f[4] = {v.x, v.y, v.z, v.w};
    u16 h[4], l[4];
#pragma unroll
    for (int k = 0; k < 4; ++k) {
        h[k] = f2bf(f[k]);
        l[k] = f2bf(f[k] - bf2f(h[k]));
    }
    ((ushort4*)hi)[i] = make_ushort4(h[0], h[1], h[2], h[3]);
    ((ushort4*)lo)[i] = make_ushort4(l[0], l[1], l[2], l[3]);
}

__global__ __launch_bounds__(256)
void prep_kernel(const float* __restrict__ x,   const float* __restrict__ W1,
                 const float* __restrict__ W2,  const float* __restrict__ Wd1,
                 const float* __restrict__ Wd2, const float* __restrict__ protos,
                 u16* __restrict__ x_h,  u16* __restrict__ x_l,
                 u16* __restrict__ W1h,  u16* __restrict__ W1l,
                 u16* __restrict__ W2h,  u16* __restrict__ W2l,
                 u16* __restrict__ Wd1h, u16* __restrict__ Wd1l,
                 u16* __restrict__ Wd2h, u16* __restrict__ Wd2l,
                 u16* __restrict__ ph,   u16* __restrict__ pl,
                 float* __restrict__ pnorm, float* __restrict__ S,
                 float* __restrict__ Mn, float* __restrict__ out)
{
    int blk = blockIdx.x, t = threadIdx.x;
    if (blk < 8192)        split4(x,   x_h,  x_l,  blk * 256 + t);
    else if (blk < 8448)   split4(W1,  W1h,  W1l,  (blk - 8192) * 256 + t);
    else if (blk < 8704)   split4(W2,  W2h,  W2l,  (blk - 8448) * 256 + t);
    else if (blk < 8768)   split4(Wd1, Wd1h, Wd1l, (blk - 8704) * 256 + t);
    else if (blk < 8896)   split4(Wd2, Wd2h, Wd2l, (blk - 8768) * 256 + t);
    else if (blk < 8928)   split4(protos, ph, pl,  (blk - 8896) * 256 + t);
    else if (blk < 8930) {
        int tt = (blk - 8928) * 256 + t;           // [0,512)
        int row = tt >> 2, q = tt & 3;
        const float* pr = protos + (size_t)row * 256 + q * 64;
        float s = 0.f;
#pragma unroll
        for (int j = 0; j < 16; ++j) {
            float4 v = *(const float4*)(pr + j * 4);
            s = fmaf(v.x, v.x, s); s = fmaf(v.y, v.y, s);
            s = fmaf(v.z, v.z, s); s = fmaf(v.w, v.w, s);
        }
        s += __shfl_xor(s, 1, 64);
        s += __shfl_xor(s, 2, 64);
        if (q == 0) pnorm[row] = s;
    } else {
        int i = (blk - 8930) * 256 + t;            // [0,16384)
        S[i] = 0.f; Mn[i] = 0.f;
        if (i == 0) { out[KL_IDX] = 0.f; out[OR_IDX] = 0.f; }
    }
}

// ---------------------------------------------------------------------------
// Split-bf16 MFMA GEMM, BM=64 x BN=128, BK=32, 4 waves, DOUBLE-buffered LDS
// (48KB, 3 blocks/CU) with counted-vmcnt pipeline, prefetch distance 2:
//   iter t: ds_read(buf t) -> lgkmcnt(0) -> barrier -> stage(t+2 -> buf t)
//           -> MFMA -> vmcnt(6) -> barrier          (never vmcnt(0) mid-loop)
// MODE 0: relu -> split store
// MODE 3: tanh -> f32 store
// MODE 4: y<2 mu split store + |mu|^2 row-reduce; y>=2 logVar -> S row-reduce
// MODE 5: y<2 relu split store (dh); y==2 proto-distance epilogue
// ---------------------------------------------------------------------------
template<int MODE, int KK>
__global__ __launch_bounds__(256, 3)
void gemm_mfma(const u16* __restrict__ Ah_g, const u16* __restrict__ Al_g,
               const u16* __restrict__ Bh_g, const u16* __restrict__ Bl_g,
               const u16* __restrict__ Ph,   const u16* __restrict__ Pl,
               const float* __restrict__ bias,
               u16* __restrict__ Ch, u16* __restrict__ Cl,
               float* __restrict__ Cf,
               float* __restrict__ Srow, float* __restrict__ Mnorm,
               const int* __restrict__ tcls, const float* __restrict__ pnorm,
               const float* __restrict__ Wlast,
               float* __restrict__ out, float* __restrict__ klrow,
               int ldc)
{
    __shared__ __align__(16) u16 LAh[2][64][32];
    __shared__ __align__(16) u16 LAl[2][64][32];
    __shared__ __align__(16) u16 LBh[2][128][32];
    __shared__ __align__(16) u16 LBl[2][128][32];

    const int t = threadIdx.x, lane = t & 63, wave = t >> 6;
    const int wm = wave >> 1, wn = wave & 1;
    const int bm = blockIdx.x * 64;
    const int y  = blockIdx.y;
    const bool proto = (MODE == 5) && (y == 2);
    const int bn = proto ? 0 : y * 128;
    const u16* Bh = proto ? Ph : Bh_g;
    const u16* Bl = proto ? Pl : Bl_g;
    const int rA = lane & 15, g = lane >> 4;
    const int srow = lane >> 2, cp = lane & 3;

    f32x4 acc[2][4];
    const f32x4 z4 = {0.f, 0.f, 0.f, 0.f};
#pragma unroll
    for (int i = 0; i < 2; ++i)
#pragma unroll
        for (int j = 0; j < 4; ++j) acc[i][j] = z4;

    auto stage = [&](int buf, int kt) {   // 6 GLD16 per wave
        {
            int row = wave * 16 + srow;
            int lc  = (cp - (row >> 1)) & 3;              // inverse swizzle on SOURCE
            size_t goff = (size_t)(bm + row) * KK + kt * 32 + lc * 8;
            GLD16(Ah_g + goff, &LAh[buf][wave * 16][0]);
            GLD16(Al_g + goff, &LAl[buf][wave * 16][0]);
        }
#pragma unroll
        for (int jj = 0; jj < 2; ++jj) {
            int row = wave * 32 + jj * 16 + srow;
            int lc  = (cp - (row >> 1)) & 3;
            size_t goff = (size_t)(bn + row) * KK + kt * 32 + lc * 8;
            GLD16(Bh + goff, &LBh[buf][wave * 32 + jj * 16][0]);
            GLD16(Bl + goff, &LBl[buf][wave * 32 + jj * 16][0]);
        }
    };

    constexpr int T = KK / 32;
    stage(0, 0);
    stage(1, 1);
    asm volatile("s_waitcnt vmcnt(6)" ::: "memory");   // stage(0) landed
    __builtin_amdgcn_sched_barrier(0);
    __builtin_amdgcn_s_barrier();

#pragma unroll
    for (int tk = 0; tk < T; ++tk) {
        const int buf = tk & 1;

        bf16x8 aH[2], aL[2], bH[4], bL[4];
#pragma unroll
        for (int i = 0; i < 2; ++i) {
            int m  = wm * 32 + i * 16 + rA;
            int cm = ((g + (m >> 1)) & 3) * 8;            // swizzled READ
            aH[i] = *(const bf16x8*)&LAh[buf][m][cm];
            aL[i] = *(const bf16x8*)&LAl[buf][m][cm];
        }
#pragma unroll
        for (int j = 0; j < 4; ++j) {
            int n  = wn * 64 + j * 16 + rA;
            int cn = ((g + (n >> 1)) & 3) * 8;
            bH[j] = *(const bf16x8*)&LBh[buf][n][cn];
            bL[j] = *(const bf16x8*)&LBl[buf][n][cn];
        }

        // my reads landed; then workgroup-wide: buf safe to overwrite
        asm volatile("s_waitcnt lgkmcnt(0)" ::: "memory");
        __builtin_amdgcn_sched_barrier(0);
        __builtin_amdgcn_s_barrier();

        if (tk + 2 < T) stage(buf, tk + 2);   // flies under the MFMAs

#pragma unroll
        for (int i = 0; i < 2; ++i)
#pragma unroll
            for (int j = 0; j < 4; ++j) {
                acc[i][j] = __builtin_amdgcn_mfma_f32_16x16x32_bf16(aH[i], bH[j], acc[i][j], 0, 0, 0);
                acc[i][j] = __builtin_amdgcn_mfma_f32_16x16x32_bf16(aL[i], bH[j], acc[i][j], 0, 0, 0);
                acc[i][j] = __builtin_amdgcn_mfma_f32_16x16x32_bf16(aH[i], bL[j], acc[i][j], 0, 0, 0);
            }

        if (tk + 1 < T) {
            if (tk + 2 < T) asm volatile("s_waitcnt vmcnt(6)" ::: "memory"); // stage(tk+1) done
            else            asm volatile("s_waitcnt vmcnt(0)" ::: "memory"); // drain last stage
            __builtin_amdgcn_sched_barrier(0);
            __builtin_amdgcn_s_barrier();
        }
    }

    if (proto) {
        // d^2 = |mu|^2 + |p|^2 - 2*cross for the class slab cols cls*16..+15
        float pn[4], wl[4];
#pragma unroll
        for (int j = 0; j < 4; ++j) {
            int col = wn * 64 + j * 16 + rA;
            pn[j] = pnorm[col];
            wl[j] = Wlast[col];
        }
#pragma unroll
        for (int i = 0; i < 2; ++i)
#pragma unroll
            for (int r = 0; r < 4; ++r) {
                int row = bm + wm * 32 + i * 16 + g * 4 + r;
                int cls = tcls[row];
                int jsel = cls & 3;
                bool owner = ((cls >> 2) == wn);
                float cv = 0.f, pnv = 0.f, wlv = 0.f;
#pragma unroll
                for (int j = 0; j < 4; ++j) {
                    bool sel = (j == jsel);
                    cv  = sel ? acc[i][j][r] : cv;
                    pnv = sel ? pn[j] : pnv;
                    wlv = sel ? wl[j] : wlv;
                }
                float dd  = fmaxf(Mnorm[row] + pnv - 2.f * cv, 0.f);
                float d   = sqrtf(dd);
                float sim = __logf((d + 1.0f) / (d + EPS_SIM));
                float kl  = Srow[row] + dd * (0.5f / 256.f);
                float klw = kl * sim;
                float num = klw;
                float den = (klw > 0.0f) ? sim : 0.0f;
                float ov  = sim * wlv;
                num += __shfl_xor(num, 1, 64); den += __shfl_xor(den, 1, 64); ov += __shfl_xor(ov, 1, 64);
                num += __shfl_xor(num, 2, 64); den += __shfl_xor(den, 2, 64); ov += __shfl_xor(ov, 2, 64);
                num += __shfl_xor(num, 4, 64); den += __shfl_xor(den, 4, 64); ov += __shfl_xor(ov, 4, 64);
                num += __shfl_xor(num, 8, 64); den += __shfl_xor(den, 8, 64); ov += __shfl_xor(ov, 8, 64);
                if (owner && rA == 0) {
                    out[row]   = ov;
                    klrow[row] = num / den;
                }
            }
        return;
    }

    float bv[4];
#pragma unroll
    for (int j = 0; j < 4; ++j) bv[j] = bias[bn + wn * 64 + j * 16 + rA];

    if (MODE == 4 && y >= 2) {
        // logVar columns: S[row] += mean_l(0.5 e^lv - 0.5 lv - 0.5)
#pragma unroll
        for (int i = 0; i < 2; ++i)
#pragma unroll
            for (int r = 0; r < 4; ++r) {
                int row = bm + wm * 32 + i * 16 + g * 4 + r;
                float s = 0.f;
#pragma unroll
                for (int j = 0; j < 4; ++j) {
                    float lv = acc[i][j][r] + bv[j];
                    lv = fminf(fmaxf(lv, LOG_MIN_F), -LOG_MIN_F);
                    s += 0.5f * __expf(lv) - 0.5f * lv - 0.5f;
                }
                s += __shfl_xor(s, 1, 64); s += __shfl_xor(s, 2, 64);
                s += __shfl_xor(s, 4, 64); s += __shfl_xor(s, 8, 64);
                if (rA == 0) atomicAdd(&Srow[row], s * (1.f / 256.f));
            }
        return;
    }

#pragma unroll
    for (int i = 0; i < 2; ++i)
#pragma unroll
        for (int r = 0; r < 4; ++r) {
            size_t row = bm + wm * 32 + i * 16 + g * 4 + r;
            float sq = 0.f;
#pragma unroll
            for (int j = 0; j < 4; ++j) {
                int col = bn + wn * 64 + j * 16 + rA;
                float v = acc[i][j][r] + bv[j];
                if (MODE == 0 || MODE == 5) v = fmaxf(v, 0.f);
                if (MODE == 3) {
                    float e = __expf(2.f * v);
                    Cf[row * ldc + col] = 1.f - 2.f / (e + 1.f);
                } else {
                    u16 hh = f2bf(v);
                    u16 ll = f2bf(v - bf2f(hh));
                    Ch[row * ldc + col] = hh;
                    Cl[row * ldc + col] = ll;
                    if (MODE == 4) sq = fmaf(v, v, sq);
                }
            }
            if (MODE == 4) {   // |mu|^2 partial for this wave's 64 cols
                sq += __shfl_xor(sq, 1, 64); sq += __shfl_xor(sq, 2, 64);
                sq += __shfl_xor(sq, 4, 64); sq += __shfl_xor(sq, 8, 64);
                if (rA == 0) atomicAdd(&Mnorm[row], sq);
            }
        }
}

__global__ __launch_bounds__(256)
void reduce_kl(const float* __restrict__ klrow, float* __restrict__ kl_out)
{
    int i = blockIdx.x * 256 + threadIdx.x;
    float v = klrow[i];
#pragma unroll
    for (int off = 32; off; off >>= 1) v += __shfl_xor(v, off, 64);
    __shared__ float red[4];
    int lane = threadIdx.x & 63, w = threadIdx.x >> 6;
    if (lane == 0) red[w] = v;
    __syncthreads();
    if (threadIdx.x == 0)
        atomicAdd(kl_out, (red[0] + red[1] + red[2] + red[3]) * (1.0f / (float)B_ROWS));
}

__global__ __launch_bounds__(256)
void ortho_kernel(const float* __restrict__ protos, float* __restrict__ ortho_out)
{
    int c = blockIdx.x;
    __shared__ float pk[PC][257];
    __shared__ float red[256];
    int t = threadIdx.x;
    for (int i = t; i < PC * 256; i += 256)
        pk[i >> 8][i & 255] = protos[c * PC * 256 + i];
    __syncthreads();
    float mean = 0.0f;
    for (int i = 0; i < PC; ++i) mean += pk[i][t];
    mean *= (1.0f / (float)PC);
    for (int i = 0; i < PC; ++i) pk[i][t] -= mean;
    __syncthreads();
    int i = t >> 4, j = t & 15;
    float gg = 0.0f;
    for (int l = 0; l < 256; ++l) gg += pk[i][l] * pk[j][l];
    gg -= (i == j) ? 1.0f : 0.0f;
    red[t] = gg * gg;
    __syncthreads();
    for (int s = 128; s; s >>= 1) { if (t < s) red[t] += red[t + s]; __syncthreads(); }
    if (t == 0) atomicAdd(ortho_out, sqrtf(red[0]) * (1.0f / 8.0f));
}

// ---------------------------------------------------------------------------
extern "C" void kernel_launch(void* const* d_in, const int* in_sizes, int n_in,
                              void* d_out, int out_size, void* d_ws, size_t ws_size,
                              hipStream_t stream)
{
    const float* x      = (const float*)d_in[0];
    const int*   tcls   = (const int*)  d_in[1];
    const float* protos = (const float*)d_in[2];
    const float* W1     = (const float*)d_in[3];
    const float* b1     = (const float*)d_in[4];
    const float* W2     = (const float*)d_in[5];
    const float* b2     = (const float*)d_in[6];
    const float* Wd1    = (const float*)d_in[7];
    const float* bd1    = (const float*)d_in[8];
    const float* Wd2    = (const float*)d_in[9];
    const float* bd2    = (const float*)d_in[10];
    const float* Wlast  = (const float*)d_in[11];

    float* out     = (float*)d_out;
    float* decoded = out + B_ROWS;

    // h (split bf16) lives in d_out's decoded region (33.55MB), overwritten by G4
    u16* h_h = (u16*)decoded;
    u16* h_l = h_h + 8388608;

    // workspace overlays: x region (32MB) reused for mu + dh after G1
    u16* wsu  = (u16*)d_ws;
    u16* x_h  = wsu;
    u16* x_l  = wsu + 8388608;
    u16* mu_h = wsu;
    u16* mu_l = wsu + 4194304;
    u16* dh_h = wsu + 8388608;
    u16* dh_l = wsu + 12582912;

    float* S     = (float*)((char*)d_ws + 33554432);
    float* klrow = S + 16384;
    u16* w = (u16*)(klrow + 16384);
    u16 *W1h = w, *W1l = w + 262144, *W2h = w + 524288, *W2l = w + 786432;
    u16 *Wd1h = w + 1048576, *Wd1l = w + 1114112, *Wd2h = w + 1179648, *Wd2l = w + 1310720;
    u16 *ph = w + 1441792, *pl = ph + 32768;       // protos split (128x256)
    float* munorm = (float*)(pl + 32768);          // 16384 f32
    float* pnorm  = munorm + 16384;                // 128 f32

    // ONE prep launch: all splits + pnorm + init (block-range dispatch)
    hipLaunchKernelGGL(prep_kernel, dim3(8994), dim3(256), 0, stream,
                       x, W1, W2, Wd1, Wd2, protos,
                       x_h, x_l, W1h, W1l, W2h, W2l, Wd1h, Wd1l, Wd2h, Wd2l,
                       ph, pl, pnorm, S, munorm, out);

    // G1: h = relu(x @ W1^T + b1) -> split bf16
    hipLaunchKernelGGL((gemm_mfma<0, 512>), dim3(256, 4), dim3(256), 0, stream,
                       x_h, x_l, W1h, W1l, (u16*)nullptr, (u16*)nullptr, b1,
                       h_h, h_l, (float*)nullptr, (float*)nullptr, (float*)nullptr,
                       (int*)nullptr, (float*)nullptr, (float*)nullptr,
                       (float*)nullptr, (float*)nullptr, 512);
    // G2: conv = h @ W2^T + b2 -> mu split + munorm (y<2); S row-sums (y>=2)
    hipLaunchKernelGGL((gemm_mfma<4, 512>), dim3(256, 4), dim3(256), 0, stream,
                       h_h, h_l, W2h, W2l, (u16*)nullptr, (u16*)nullptr, b2,
                       mu_h, mu_l, (float*)nullptr, S, munorm,
                       (int*)nullptr, (float*)nullptr, (float*)nullptr,
                       (float*)nullptr, (float*)nullptr, 256);
    // G3': y<2: dh = relu(mu @ Wd1^T + bd1); y==2: proto distances + sim/kl/out
    hipLaunchKernelGGL((gemm_mfma<5, 256>), dim3(256, 3), dim3(256), 0, stream,
                       mu_h, mu_l, Wd1h, Wd1l, ph, pl, bd1,
                       dh_h, dh_l, (float*)nullptr, S, munorm,
                       tcls, pnorm, Wlast, out, klrow, 256);
    hipLaunchKernelGGL(reduce_kl, dim3(64), dim3(256), 0, stream, klrow, out + KL_IDX);
    // G4: decoded = tanh(dh @ Wd2^T + bd2) -> f32 (overwrites h region)
    hipLaunchKernelGGL((gemm_mfma<3, 256>), dim3(256, 4), dim3(256), 0, stream,
                       dh_h, dh_l, Wd2h, Wd2l, (u16*)nullptr, (u16*)nullptr, bd2,
                       (u16*)nullptr, (u16*)nullptr, decoded, (float*)nullptr, (float*)nullptr,
                       (int*)nullptr, (float*)nullptr, (float*)nullptr,
                       (float*)nullptr, (float*)nullptr, 512);
    hipLaunchKernelGGL(ortho_kernel, dim3(8), dim3(256), 0, stream, protos, out + OR_IDX);
}